// Round 6
// baseline (106.210 us; speedup 1.0000x reference)
//
#include <hip/hip_runtime.h>

typedef short short8 __attribute__((ext_vector_type(8)));
typedef float f32x4 __attribute__((ext_vector_type(4)));

#define BN_EPS 1e-5f
#define CUT_THRESH 1e-3f
#define NT 3  // row-tiles per block

// ws layout (bytes):
//   [0, 18432)        wbf  (9216 bf16, [kk][co][ci] ci-octet ^ ((co>>1)&3) swizzle)
//   [18432, 18688)    coef (64 f32: scl[0:32], sft[32:64])
//   [18688, +196608)  part (1024 planes x 48 blocks f32 partial plane-maxes)
#define WS_COEF 18432
#define WS_PART 18688

__device__ __forceinline__ unsigned short f2bf(float f) {
  unsigned u = __float_as_uint(f);
  u += 0x7FFFu + ((u >> 16) & 1u);  // RNE (prep only)
  return (unsigned short)(u >> 16);
}

__device__ __forceinline__ void gload_lds16(const void* g, void* l) {
  __builtin_amdgcn_global_load_lds(
      (const __attribute__((address_space(1))) unsigned int*)g,
      (__attribute__((address_space(3))) unsigned int*)l, 16, 0, 0);
}

// One-time weight conversion + BN coefficient fusion.
__global__ void prep_kernel(const float* __restrict__ wgt,
                            const float* __restrict__ bias,
                            const float* __restrict__ gamma,
                            const float* __restrict__ beta,
                            const float* __restrict__ rmean,
                            const float* __restrict__ rvar,
                            unsigned short* __restrict__ wbf,
                            float* __restrict__ coef) {
  int tid = blockIdx.x * 256 + threadIdx.x;
  if (tid < 9216) {
    int co = tid / 288;  // wgt is OIHW
    int rem = tid - co * 288;
    int ci = rem / 9;
    int kk = rem - ci * 9;
    int oct = ((ci >> 3) ^ ((co >> 1) & 3)) << 3;
    wbf[(kk * 32 + co) * 32 + oct + (ci & 7)] = f2bf(wgt[tid]);
  }
  if (tid < 32) {
    float s = gamma[tid] * rsqrtf(rvar[tid] + BN_EPS);
    coef[tid] = s;
    coef[32 + tid] = (bias[tid] - rmean[tid]) * s + beta[tid];
  }
}

// Phase 1 of staging: issue all 48 independent x-loads for one 10x34 tile.
__device__ __forceinline__ void issue_tile(const float* __restrict__ xb, int r0,
                                           int c0, int tid, int m80,
                                           float fv[6][8], int okm[6]) {
#pragma unroll
  for (int r = 0; r < 6; ++r) {
    int id = (r < 5) ? (r * 256 + tid) : (1280 + m80);
    int g = id & 3;
    int p = id >> 2;  // h*34 + w
    int h = p / 34;
    int w = p - h * 34;
    int gh = r0 - 1 + h, gw = c0 - 1 + w;
    okm[r] = (((unsigned)gh < 192u) && ((unsigned)gw < 192u)) ? -1 : 0;
    int ghc = min(max(gh, 0), 191);
    int gwc = min(max(gw, 0), 191);
    const float* src = xb + (g * 8) * 36864 + ghc * 192 + gwc;
#pragma unroll
    for (int j = 0; j < 8; ++j) fv[r][j] = src[j * 36864];  // 48 in flight
  }
}

// Phase 2: convert (round-half-up) + swizzled ds_write_b128 into lxb.
__device__ __forceinline__ void write_tile(unsigned short* __restrict__ lxb,
                                           int tid, int m80,
                                           const float fv[6][8],
                                           const int okm[6]) {
#pragma unroll
  for (int r = 0; r < 6; ++r) {
    int id = (r < 5) ? (r * 256 + tid) : (1280 + m80);
    int g = id & 3;
    int p = id >> 2;
    int w = p - (p / 34) * 34;
    unsigned pk[4];
#pragma unroll
    for (int q = 0; q < 4; ++q) {
      float f0 = okm[r] ? fv[r][2 * q] : 0.f;
      float f1 = okm[r] ? fv[r][2 * q + 1] : 0.f;
      unsigned a = __float_as_uint(f0) + 0x8000u;
      unsigned c = __float_as_uint(f1) + 0x8000u;
      pk[q] = (a >> 16) | (c & 0xffff0000u);
    }
    short8 v;
    reinterpret_cast<unsigned*>(&v)[0] = pk[0];
    reinterpret_cast<unsigned*>(&v)[1] = pk[1];
    reinterpret_cast<unsigned*>(&v)[2] = pk[2];
    reinterpret_cast<unsigned*>(&v)[3] = pk[3];
    *reinterpret_cast<short8*>(&lxb[p * 32 + ((g ^ ((w >> 1) & 3)) << 3)]) = v;
  }
}

// Implicit-GEMM conv 3x3 + BN + ReLU; block = 3 stacked 8x32 tiles x 32 co,
// double-buffered LDS, async-stage pipeline (loads for tile i+1 in flight
// during tile i's MFMA + epilogue).
__global__ __launch_bounds__(256, 2) void conv_bn_relu_kernel(
    const float* __restrict__ x,
    const unsigned short* __restrict__ wbf,
    const float* __restrict__ coef,
    float* __restrict__ out,
    float* __restrict__ part) {
  __shared__ unsigned short lx[2][10 * 34 * 32];  // 2 x 21760 B
  __shared__ unsigned short lw[9 * 32 * 32];      // 18432 B
  __shared__ float red[4][32];                    // 512 B -> total 62464 B

  int bid = blockIdx.x;
  int orig = (bid & 7) * 192 + (bid >> 3);  // XCD-bijective: 1536 = 8*192
  int b = orig / 48;
  int rem = orig - b * 48;
  int tc = rem >> 3;  // 0..5
  int rg = rem & 7;   // 0..7
  int c0 = tc * 32;
  int r0b = rg * 24;  // this block covers rows r0b .. r0b+23
  int tid = threadIdx.x;

  // weights: 1152 x 16B DMA chunks (drained by prologue's vmcnt wait + barrier)
  {
    const short8* wsrc = reinterpret_cast<const short8*>(wbf);
    short8* wdst = reinterpret_cast<short8*>(lw);
#pragma unroll
    for (int r = 0; r < 4; ++r) gload_lds16(wsrc + r * 256 + tid, wdst + r * 256 + tid);
    if (tid < 128) gload_lds16(wsrc + 1024 + tid, wdst + 1024 + tid);
  }

  const float* xb = x + b * (32 * 192 * 192);
  int m80 = tid;
  m80 = (m80 >= 160) ? m80 - 160 : m80;
  m80 = (m80 >= 80) ? m80 - 80 : m80;

  int lane = tid & 63;
  int wv = tid >> 6;
  int l15 = lane & 15;
  int lg = lane >> 4;
  int aswz = (lg ^ ((l15 >> 1) & 3)) << 3;

  f32x4 scl[2], sft[2];
#pragma unroll
  for (int m = 0; m < 2; ++m) {
    scl[m] = *reinterpret_cast<const f32x4*>(coef + m * 16 + lg * 4);
    sft[m] = *reinterpret_cast<const f32x4*>(coef + 32 + m * 16 + lg * 4);
  }

  float fv[6][8];
  int okm[6];

  // ---- prologue: stage tile 0 (one exposed round trip per block) ----
  issue_tile(xb, r0b, c0, tid, m80, fv, okm);
  __builtin_amdgcn_sched_barrier(0);
  write_tile(lx[0], tid, m80, fv, okm);
  __syncthreads();

  const int HW = 192 * 192;
  float* ob = out + b * 32 * HW;
  float pmax[2][4];
#pragma unroll
  for (int m = 0; m < 2; ++m)
#pragma unroll
    for (int j = 0; j < 4; ++j) pmax[m][j] = 0.f;

#pragma unroll
  for (int i = 0; i < NT; ++i) {
    int r0 = r0b + 8 * i;

    // issue next tile's loads FIRST — latency hides under MFMA + epilogue
    if (i + 1 < NT) {
      issue_tile(xb, r0 + 8, c0, tid, m80, fv, okm);
      __builtin_amdgcn_sched_barrier(0);
    }

    const unsigned short* lxp = lx[i & 1];
    f32x4 acc[2][4] = {};
#pragma unroll
    for (int s = 0; s < 9; ++s) {
      const int kh = s / 3, kw = s - kh * 3;
      short8 A0 = *reinterpret_cast<const short8*>(&lw[(s * 32 + l15) * 32 + aswz]);
      short8 A1 = *reinterpret_cast<const short8*>(&lw[(s * 32 + 16 + l15) * 32 + aswz]);
#pragma unroll
      for (int n = 0; n < 4; ++n) {
        int hl = 2 * wv + (n >> 1) + kh;
        int wl = ((n & 1) << 4) + l15 + kw;
        short8 Bf = *reinterpret_cast<const short8*>(
            &lxp[(hl * 34 + wl) * 32 + ((lg ^ ((wl >> 1) & 3)) << 3)]);
        acc[0][n] = __builtin_amdgcn_mfma_f32_16x16x32_bf16(A0, Bf, acc[0][n], 0, 0, 0);
        acc[1][n] = __builtin_amdgcn_mfma_f32_16x16x32_bf16(A1, Bf, acc[1][n], 0, 0, 0);
      }
    }

    // epilogue: BN + ReLU + store + plane-max accumulation (no barrier)
#pragma unroll
    for (int m = 0; m < 2; ++m)
#pragma unroll
      for (int n = 0; n < 4; ++n) {
        int gr = r0 + 2 * wv + (n >> 1);
        int gc = c0 + ((n & 1) << 4) + l15;
#pragma unroll
        for (int j = 0; j < 4; ++j) {
          int co = m * 16 + lg * 4 + j;  // D row = (lane>>4)*4 + reg (m89)
          float v = fmaxf(acc[m][n][j] * scl[m][j] + sft[m][j], 0.f);
          ob[co * HW + gr * 192 + gc] = v;
          pmax[m][j] = fmaxf(pmax[m][j], v);
        }
      }

    // convert + ds_write next tile into the other buffer, then barrier
    if (i + 1 < NT) {
      __builtin_amdgcn_sched_barrier(0);  // keep cvt AFTER mfma/epilogue
      write_tile(lx[(i + 1) & 1], tid, m80, fv, okm);
    }
    __syncthreads();
  }

  // 16-lane reduce -> red -> block reduce -> 32 contiguous part floats
#pragma unroll
  for (int m = 0; m < 2; ++m)
#pragma unroll
    for (int j = 0; j < 4; ++j) {
      float v = pmax[m][j];
      v = fmaxf(v, __shfl_xor(v, 1, 16));
      v = fmaxf(v, __shfl_xor(v, 2, 16));
      v = fmaxf(v, __shfl_xor(v, 4, 16));
      v = fmaxf(v, __shfl_xor(v, 8, 16));
      if (l15 == 0) red[wv][m * 16 + lg * 4 + j] = v;
    }
  __syncthreads();
  if (tid < 32) {
    float mx = fmaxf(fmaxf(red[0][tid], red[1][tid]),
                     fmaxf(red[2][tid], red[3][tid]));
    part[((size_t)b * 32 + tid) * 48 + (tc << 3) + rg] = mx;
  }
}

// Per (b,co) plane: reduce 48 contiguous partials; zero plane if < thresh.
__global__ __launch_bounds__(256) void cut_kernel(float* __restrict__ out,
                                                  const float* __restrict__ part) {
  __shared__ float r4[4];
  int p = blockIdx.x;  // b*32 + co
  const float* pp = part + (size_t)p * 48;
  float m = 0.f;
  if (threadIdx.x < 48) m = pp[threadIdx.x];
#pragma unroll
  for (int k = 1; k < 64; k <<= 1) m = fmaxf(m, __shfl_xor(m, k, 64));
  if ((threadIdx.x & 63) == 0) r4[threadIdx.x >> 6] = m;
  __syncthreads();
  m = fmaxf(fmaxf(r4[0], r4[1]), fmaxf(r4[2], r4[3]));
  if (m >= CUT_THRESH) return;  // uniform; never fires on this data
  float* base = out + (size_t)p * 36864;
  for (int i = threadIdx.x; i < 36864; i += 256) base[i] = 0.f;
}

extern "C" void kernel_launch(void* const* d_in, const int* in_sizes, int n_in,
                              void* d_out, int out_size, void* d_ws, size_t ws_size,
                              hipStream_t stream) {
  const float* x     = (const float*)d_in[0];
  const float* wgt   = (const float*)d_in[1];
  const float* bias  = (const float*)d_in[2];
  const float* gamma = (const float*)d_in[3];
  const float* beta  = (const float*)d_in[4];
  const float* rmean = (const float*)d_in[5];
  const float* rvar  = (const float*)d_in[6];
  float* out = (float*)d_out;

  unsigned short* wbf  = (unsigned short*)d_ws;
  float*          coef = (float*)((char*)d_ws + WS_COEF);
  float*          part = (float*)((char*)d_ws + WS_PART);

  prep_kernel<<<36, 256, 0, stream>>>(wgt, bias, gamma, beta, rmean, rvar, wbf, coef);
  conv_bn_relu_kernel<<<1536, 256, 0, stream>>>(x, wbf, coef, out, part);
  cut_kernel<<<1024, 256, 0, stream>>>(out, part);
}